// Round 3
// baseline (1142.683 us; speedup 1.0000x reference)
//
#include <hip/hip_runtime.h>
#include <hip/hip_bf16.h>

#define VOCAB 4096
#define BB 4
#define LL 2048
#define SEG 16
#define SEGL 128  // LL/SEG

typedef __hip_bfloat16 bf16;
typedef __bf16 bf16x8 __attribute__((ext_vector_type(8)));
typedef float f32x4 __attribute__((ext_vector_type(4)));

__device__ __forceinline__ void gload16(const void* g, void* l) {
  __builtin_amdgcn_global_load_lds(
      (const __attribute__((address_space(1))) unsigned int*)g,
      (__attribute__((address_space(3))) unsigned int*)l, 16, 0, 0);
}

// ---------------- transpose f32 [K][N] -> bf16 [N][K] ----------------
__global__ void transpose_f32_bf16(const float* __restrict__ in,
                                   bf16* __restrict__ out, int K, int N) {
  __shared__ float tile[32][33];
  int bx = blockIdx.x;  // tile along N
  int by = blockIdx.y;  // tile along K
  int x = bx * 32 + threadIdx.x;
#pragma unroll
  for (int i = threadIdx.y; i < 32; i += 8)
    tile[i][threadIdx.x] = in[(size_t)(by * 32 + i) * N + x];
  __syncthreads();
  int k = by * 32 + threadIdx.x;
#pragma unroll
  for (int i = threadIdx.y; i < 32; i += 8)
    out[(size_t)(bx * 32 + i) * K + k] = __float2bfloat16(tile[threadIdx.x][i]);
}

// -------- ctx pass A: per-segment sigmoid column sums --------
__global__ void ctx_partial(const int* __restrict__ idx,
                            const float* __restrict__ Mlog,
                            float* __restrict__ segsum) {
  int b = blockIdx.x / (16 * SEG);
  int rem = blockIdx.x % (16 * SEG);
  int chunk = rem / SEG;
  int s = rem % SEG;
  int col = chunk * 256 + threadIdx.x;
  __shared__ int sidx[SEGL];
  if (threadIdx.x < SEGL)
    sidx[threadIdx.x] = idx[b * LL + s * SEGL + threadIdx.x];
  __syncthreads();
  const float* base = Mlog + col;
  float a0 = 0.f, a1 = 0.f, a2 = 0.f, a3 = 0.f;
#pragma unroll 4
  for (int t = 0; t < SEGL; t += 4) {
    float v0 = base[(size_t)sidx[t + 0] * VOCAB];
    float v1 = base[(size_t)sidx[t + 1] * VOCAB];
    float v2 = base[(size_t)sidx[t + 2] * VOCAB];
    float v3 = base[(size_t)sidx[t + 3] * VOCAB];
    a0 += 1.f / (1.f + __expf(-v0));
    a1 += 1.f / (1.f + __expf(-v1));
    a2 += 1.f / (1.f + __expf(-v2));
    a3 += 1.f / (1.f + __expf(-v3));
  }
  segsum[(size_t)blockIdx.x * 256 + threadIdx.x] = (a0 + a1) + (a2 + a3);
}

// -------- ctx pass B: replay segment with offset, write running mean --------
__global__ void ctx_final(const int* __restrict__ idx,
                          const float* __restrict__ Mlog,
                          const float* __restrict__ segsum,
                          bf16* __restrict__ ctx) {
  int b = blockIdx.x / (16 * SEG);
  int rem = blockIdx.x % (16 * SEG);
  int chunk = rem / SEG;
  int s = rem % SEG;
  int col = chunk * 256 + threadIdx.x;
  __shared__ int sidx[SEGL];
  if (threadIdx.x < SEGL)
    sidx[threadIdx.x] = idx[b * LL + s * SEGL + threadIdx.x];
  __syncthreads();
  const float* ss = segsum + (size_t)((b * 16 + chunk) * SEG) * 256 + threadIdx.x;
  float acc = 0.f;
  for (int s2 = 0; s2 < s; ++s2) acc += ss[(size_t)s2 * 256];
  const float* base = Mlog + col;
  bf16* outp = ctx + ((size_t)b * LL + (size_t)s * SEGL) * VOCAB + col;
#pragma unroll 8
  for (int t = 0; t < SEGL; ++t) {
    float v = base[(size_t)sidx[t] * VOCAB];
    acc += 1.f / (1.f + __expf(-v));
    float inv = __fdividef(1.f, (float)(s * SEGL + t + 1));
    outp[(size_t)t * VOCAB] = __float2bfloat16(acc * inv);
  }
}

// ---------------- 256x256 8-phase bf16 GEMM: C = A[M][K] * Bt[N][K]^T + bias
// 512 thr (2x4 waves), BK=64, 128KiB LDS dbuf, chunk-XOR swizzle (0 conflicts),
// deep-prefetch FIFO: stages {ph1:B(t+1,h0), ph2:A(t+2,h0), ph3:A(t+1,h1),
// ph4:B(t+2,h1)}; waits vmcnt(6) at ph1/ph3 only (>=4-phase issue->wait gap).
// EPI==0: out = bf16 gelu_exact(C)   EPI==1: out = f32 C

#define BAR() asm volatile("s_barrier" ::: "memory")
#define LGKM0() asm volatile("s_waitcnt lgkmcnt(0)" ::: "memory")
#define VMW(n_) asm volatile("s_waitcnt vmcnt(" #n_ ")" ::: "memory")

// stage one half-tile (128 rows x 64 cols) of A or B into buffer b
#define STG_A(t_, h_, b_)                                           \
  {                                                                 \
    const bf16* s_ = Asrc + (size_t)(h_)*128 * K + (size_t)(t_)*64; \
    bf16* d_ = sm + (b_)*32768 + (h_)*8192 + wave * 512;            \
    gload16(s_, d_);                                                \
    gload16(s_ + rowK64, d_ + 4096);                                \
  }
#define STG_B(t_, h_, b_)                                           \
  {                                                                 \
    const bf16* s_ = Bsrc + (size_t)(h_)*128 * K + (size_t)(t_)*64; \
    bf16* d_ = sm + (b_)*32768 + 16384 + (h_)*8192 + wave * 512;    \
    gload16(s_, d_);                                                \
    gload16(s_ + rowK64, d_ + 4096);                                \
  }

// fragment load: slot = row*8 + (kc ^ (row&7)); row&7 == rsel&7 == xorv
#define LDF(base_, row_, kc_) \
  (*(const bf16x8*)((base_) + (row_)*64 + ((((kc_) ^ xorv)) << 3)))

#define LOAD_A(mh_)                                  \
  _Pragma("unroll") for (int i_ = 0; i_ < 4; ++i_) { \
    int row_ = (mh_)*128 + wm64 + i_ * 16 + rsel;    \
    af[i_][0] = LDF(Ab, row_, ksel);                 \
    af[i_][1] = LDF(Ab, row_, 4 + ksel);             \
  }
#define LOAD_B(nh_)                                  \
  _Pragma("unroll") for (int j_ = 0; j_ < 2; ++j_) { \
    int row_ = (nh_)*128 + wn32 + j_ * 16 + rsel;    \
    bfr[j_][0] = LDF(Bb, row_, ksel);                \
    bfr[j_][1] = LDF(Bb, row_, 4 + ksel);            \
  }

#define MFMAQ(mh_, nh_)                                                        \
  _Pragma("unroll") for (int i_ = 0; i_ < 4; ++i_)                             \
      _Pragma("unroll") for (int j_ = 0; j_ < 2; ++j_) {                       \
    f32x4& a_ = acc[(mh_)*4 + i_][(nh_)*2 + j_];                               \
    a_ = __builtin_amdgcn_mfma_f32_16x16x32_bf16(af[i_][0], bfr[j_][0], a_, 0, \
                                                 0, 0);                        \
    a_ = __builtin_amdgcn_mfma_f32_16x16x32_bf16(af[i_][1], bfr[j_][1], a_, 0, \
                                                 0, 0);                        \
  }

#define MFMA_TAIL(mh_, nh_)           \
  BAR();                              \
  LGKM0();                            \
  __builtin_amdgcn_s_setprio(1);      \
  MFMAQ(mh_, nh_);                    \
  __builtin_amdgcn_s_setprio(0);

template <int EPI>
__global__ __launch_bounds__(512, 2) void gemm256(const bf16* __restrict__ A,
                                                  const bf16* __restrict__ Bt,
                                                  const float* __restrict__ bias,
                                                  void* __restrict__ outv,
                                                  int M, int N, int K) {
  __shared__ __align__(16) bf16 sm[65536];  // 128 KiB: 2 x (A 32KB | B 32KB)
  const int tid = threadIdx.x;
  const int wave = tid >> 6;
  const int lane = tid & 63;
  const int nwg = gridDim.x;
  const int bid = blockIdx.x;
  const int swz = (bid & 7) * (nwg >> 3) + (bid >> 3);  // nwg % 8 == 0
  const int gn = N >> 8;
  const int bm0 = (swz / gn) << 8;
  const int bn0 = (swz % gn) << 8;
  const int wm64 = (wave >> 2) << 6;  // wave_m * 64
  const int wn32 = (wave & 3) << 5;   // wave_n * 32
  const int rsel = lane & 15;
  const int ksel = lane >> 4;
  const int xorv = rsel & 7;

  // staging source: thread covers slots tid and tid+512 of each half-tile;
  // slot p -> row=p>>3, kc=(p&7)^(row&7)
  const int r0 = tid >> 3;
  const int kc0 = (tid & 7) ^ (r0 & 7);
  const bf16* Asrc = A + (size_t)(bm0 + r0) * K + kc0 * 8;
  const bf16* Bsrc = Bt + (size_t)(bn0 + r0) * K + kc0 * 8;
  const size_t rowK64 = (size_t)64 * K;
  const int NT = K >> 6;

  f32x4 acc[8][4];
#pragma unroll
  for (int i = 0; i < 8; ++i)
#pragma unroll
    for (int j = 0; j < 4; ++j) acc[i][j] = (f32x4){0.f, 0.f, 0.f, 0.f};

  // prologue FIFO (order matters for the in-loop vmcnt counts):
  STG_A(0, 0, 0);  // A(0,h0)
  STG_B(0, 1, 0);  // B(0,h1)
  STG_B(0, 0, 0);  // B(0,h0)
  STG_A(1, 0, 1);  // A(1,h0)
  STG_A(0, 1, 0);  // A(0,h1)
  STG_B(1, 1, 1);  // B(1,h1)

  bf16x8 af[4][2], bfr[2][2];
  for (int t = 0; t < NT; ++t) {
    const int bc = t & 1;
    const int bnx = bc ^ 1;
    const bf16* Ab = sm + bc * 32768;
    const bf16* Bb = Ab + 16384;

    // ---- ph1: reads A0,B0 ; stages B(t+1,h0) -> bufn ----
    if (t + 1 < NT) { VMW(6); } else { VMW(2); }
    BAR();
    LOAD_A(0);
    LOAD_B(0);
    if (t + 1 < NT) STG_B(t + 1, 0, bnx);
    MFMA_TAIL(0, 0);

    // ---- ph2: reads B1 ; stages A(t+2,h0) -> bc (A0 region dead) ----
    BAR();
    LOAD_B(1);
    if (t + 2 < NT) STG_A(t + 2, 0, bc);
    MFMA_TAIL(0, 1);

    // ---- ph3: reads A1 ; stages A(t+1,h1) -> bufn ----
    if (t + 2 < NT) { VMW(6); }
    else if (t + 1 < NT) { VMW(4); }
    else { VMW(0); }
    BAR();
    LOAD_A(1);
    if (t + 1 < NT) STG_A(t + 1, 1, bnx);
    MFMA_TAIL(1, 1);

    // ---- ph4: re-reads B0 ; stages B(t+2,h1) -> bc (B1 region dead) ----
    BAR();
    LOAD_B(0);
    if (t + 2 < NT) STG_B(t + 2, 1, bc);
    MFMA_TAIL(1, 0);
  }

  // epilogue; C/D layout: col = lane&15, row = (lane>>4)*4 + reg
  const int cl = lane & 15;
  const int rg = lane >> 4;
#pragma unroll
  for (int m = 0; m < 8; ++m) {
    int grow = bm0 + ((m >> 2) << 7) + wm64 + ((m & 3) << 4) + rg * 4;
#pragma unroll
    for (int n = 0; n < 4; ++n) {
      int col = bn0 + ((n >> 1) << 7) + wn32 + ((n & 1) << 4) + cl;
      float bv = bias[col];
#pragma unroll
      for (int r = 0; r < 4; ++r) {
        size_t o = (size_t)(grow + r) * N + col;
        float v = acc[m][n][r] + bv;
        if (EPI == 0) {
          float g = 0.5f * v * (1.f + erff(v * 0.70710678118654752f));
          ((bf16*)outv)[o] = __float2bfloat16(g);
        } else {
          ((float*)outv)[o] = v;
        }
      }
    }
  }
}

extern "C" void kernel_launch(void* const* d_in, const int* in_sizes, int n_in,
                              void* d_out, int out_size, void* d_ws,
                              size_t ws_size, hipStream_t stream) {
  const int* idx = (const int*)d_in[0];       // [B,L]
  const float* Mlog = (const float*)d_in[1];  // [V,V]
  const float* W1 = (const float*)d_in[2];    // [V,2V]
  const float* b1 = (const float*)d_in[3];    // [2V]
  const float* W2 = (const float*)d_in[4];    // [2V,V]
  const float* b2 = (const float*)d_in[5];    // [V]
  float* out = (float*)d_out;                 // [B,L,V] f32

  char* ws = (char*)d_ws;
  const size_t MB64 = 64ull << 20;
  bf16* ctx = (bf16*)ws;             // 64 MiB  [8192][4096] (dead after GEMM1)
  bf16* W2t = (bf16*)ws;             // aliases ctx: [4096][8192]
  bf16* W1t = (bf16*)(ws + MB64);    // 64 MiB  [8192][4096]
  bf16* h = (bf16*)(ws + 2 * MB64);  // 128 MiB [8192][8192]
  float* segsum = (float*)h;         // 1 MiB, dead before GEMM1 writes h
  (void)ws_size;

  dim3 tb(32, 8);
  // W1^T cast
  transpose_f32_bf16<<<dim3(8192 / 32, 4096 / 32), tb, 0, stream>>>(W1, W1t,
                                                                    4096, 8192);
  // ctx = causal-mean(sigmoid(M)[idx]), segment-parallel two-pass
  ctx_partial<<<BB * 16 * SEG, 256, 0, stream>>>(idx, Mlog, segsum);
  ctx_final<<<BB * 16 * SEG, 256, 0, stream>>>(idx, Mlog, segsum, ctx);
  // h = gelu(ctx @ W1 + b1)  -> bf16
  gemm256<0><<<(8192 / 256) * (8192 / 256), 512, 0, stream>>>(
      ctx, W1t, b1, h, 8192, 8192, 4096);
  // W2^T cast (reuses ctx space)
  transpose_f32_bf16<<<dim3(4096 / 32, 8192 / 32), tb, 0, stream>>>(W2, W2t,
                                                                    8192, 4096);
  // out = h @ W2 + b2  -> f32
  gemm256<1><<<(8192 / 256) * (4096 / 256), 512, 0, stream>>>(
      h, W2t, b2, out, 8192, 4096, 8192);
}